// Round 4
// baseline (434.399 us; speedup 1.0000x reference)
//
#include <hip/hip_runtime.h>
#include <hip/hip_bf16.h>

// Problem constants
#define B_    32
#define C_    256     // Cin == Cout
#define H_    56
#define W_    56
#define HP    58      // padded H
#define WPAD  58      // padded W
#define HW    3136    // H_*W_
#define CHW   802816  // C_*H_*W_
#define M_TOT 100352  // B_*H_*W_

typedef int intx4 __attribute__((ext_vector_type(4)));

#define XPAD_BYTES (B_ * HP * WPAD * C_)        // 27,557,888 (i8)
#define WPK_BYTES  (C_ * 9 * C_)                // 589,824 (i8)

__device__ __forceinline__ int sgn8(float f) {
  return ((f > 0.f) ? 1 : ((f < 0.f) ? -1 : 0)) & 0xff;
}

// ---------------------------------------------------------------------------
// Merged pack kernel: blocks [0, B_*HP) run the pack_x role (sign(x) NCHW
// fp32 -> padded NHWC i8), blocks [B_*HP, B_*HP+C_) run the pack_w role
// (wq[co][s][ci] i8 = sign(w1)+sign(w2), alphah[co]).
// ---------------------------------------------------------------------------
#define ROWPC 272
__global__ __launch_bounds__(256) void pack_kernel(const float* __restrict__ in,
                                                   const float* __restrict__ w1,
                                                   const float* __restrict__ w2,
                                                   char* __restrict__ xp,
                                                   char* __restrict__ wq,
                                                   float* __restrict__ alphah) {
  __shared__ char smem[18448];
  const int tid = threadIdx.x;

  if (blockIdx.x < B_ * HP) {
    // ---------------- pack_x role ----------------
    char* row = smem;   // 58 * ROWPC = 15776 B
    const int yp = blockIdx.x % HP;
    const int b  = blockIdx.x / HP;

    float4* rz = (float4*)row;
    const float4 z4 = make_float4(0.f, 0.f, 0.f, 0.f);
#pragma unroll
    for (int i = 0; i < 4; ++i) {
      const int idx = i * 256 + tid;
      if (idx < (58 * ROWPC) / 16) rz[idx] = z4;
    }
    __syncthreads();

    const int y = yp - 1;
    const int xq = tid % 14;   // x quad: x = xq*4 .. xq*4+3
    const int cs = tid / 14;   // ci-quad slot 0..18 (252..255 idle)
    if (y >= 0 && y < H_ && cs < 18) {
      const float* base = in + ((size_t)b * C_ * H_ + (size_t)y) * W_ + xq * 4;
#pragma unroll
      for (int k = 0; k < 4; ++k) {
        const int cq = cs + 18 * k;          // ci quad index 0..63
        if (cq < 64) {
          float4 f[4];
#pragma unroll
          for (int j = 0; j < 4; ++j)
            f[j] = *(const float4*)(base + (size_t)(cq * 4 + j) * (H_ * W_));
#pragma unroll
          for (int d = 0; d < 4; ++d) {
            const float v0 = (d == 0) ? f[0].x : (d == 1) ? f[0].y : (d == 2) ? f[0].z : f[0].w;
            const float v1 = (d == 0) ? f[1].x : (d == 1) ? f[1].y : (d == 2) ? f[1].z : f[1].w;
            const float v2 = (d == 0) ? f[2].x : (d == 1) ? f[2].y : (d == 2) ? f[2].z : f[2].w;
            const float v3 = (d == 0) ? f[3].x : (d == 1) ? f[3].y : (d == 2) ? f[3].z : f[3].w;
            const unsigned int pk = (unsigned)sgn8(v0) | ((unsigned)sgn8(v1) << 8) |
                                    ((unsigned)sgn8(v2) << 16) | ((unsigned)sgn8(v3) << 24);
            *(unsigned int*)&row[(xq * 4 + d + 1) * ROWPC + cq * 4] = pk;
          }
        }
      }
    }
    __syncthreads();

    const int cc = tid & 15;   // 16 chunks = full 256 B ci-row
    const int xo = tid >> 4;   // 16 x per iter
    char* dst = xp + (size_t)(b * HP + yp) * WPAD * C_;
#pragma unroll
    for (int it = 0; it < 4; ++it) {
      const int xs = it * 16 + xo;
      if (xs < WPAD)
        *(float4*)(dst + xs * C_ + cc * 16) = *(const float4*)&row[xs * ROWPC + cc * 16];
    }
  } else {
    // ---------------- pack_w role ----------------
    float* l1 = (float*)smem;          // 2304 f
    float* l2 = l1 + 2304;             // 2304 f
    float* red = (float*)(smem + 18432);  // 4 f
    const int co = blockIdx.x - B_ * HP;
    const float* s1 = w1 + co * 2304;
    const float* s2 = w2 + co * 2304;
#pragma unroll
    for (int i = 0; i < 9; ++i) {       // stride-1 across lanes: coalesced
      l1[i * 256 + tid] = s1[i * 256 + tid];
      l2[i * 256 + tid] = s2[i * 256 + tid];
    }
    __syncthreads();
    const int ci = tid;
    float sabs = 0.f;
#pragma unroll
    for (int s = 0; s < 9; ++s) {       // LDS stride 9 (odd) -> bank-spread
      const float a = l1[ci * 9 + s];
      const float b = l2[ci * 9 + s];
      const int sa = (a > 0.f) - (a < 0.f);
      const int sb = (b > 0.f) - (b < 0.f);
      wq[(co * 9 + s) * C_ + ci] = (char)(sa + sb);   // coalesced byte store
      sabs += fabsf(a) + fabsf(b);
    }
#pragma unroll
    for (int off = 32; off > 0; off >>= 1) sabs += __shfl_down(sabs, off, 64);
    if ((tid & 63) == 0) red[tid >> 6] = sabs;
    __syncthreads();
    if (tid == 0)
      alphah[co] = (red[0] + red[1] + red[2] + red[3]) * (0.5f / 2304.0f);
  }
}

// ---------------------------------------------------------------------------
// Implicit-GEMM conv, int8. Round-3 kernel with ONE change: 3 blocks/CU
// (__launch_bounds__(256,3); LDS 48KB*3 = 144 <= 160 KB). 784 tiles over
// 768 resident slots = 1.02 dispatch rounds -- fixes R3's 1.53-round
// quantization (the half-empty second round ran drain-exposed at ~1/CU).
// Geometry: BM=128(co) x BN=256(m) x BK=64; each of 4 waves computes the
// full 128co x 64m (8x4 frags): 12 ds_read_b128 feed 32 MFMA per K-step.
// 36 K-steps (9 taps x 4 ci-quarters). Swizzle: chunk ^= (row>>1)&3
// (0-conflict verified in R3 counters).
// ---------------------------------------------------------------------------
#define GLL16(src, dst)                                                        \
  __builtin_amdgcn_global_load_lds(                                            \
      (const __attribute__((address_space(1))) void*)(src),                    \
      (__attribute__((address_space(3))) void*)(dst), 16, 0, 0)

__global__ __launch_bounds__(256, 3) void gemm_kernel(const char* __restrict__ xp,
                                                      const char* __restrict__ wq,
                                                      const float* __restrict__ alphah,
                                                      float* __restrict__ out) {
  __shared__ char sA[2 * 128 * 64];   // 16 KB: [buf][co 128][64B]
  __shared__ char sB[2 * 256 * 64];   // 32 KB: [buf][m 256][64B]
  const int tid = threadIdx.x;

  // XCD-paired decode (784 = 8*98, bijective): blocks id, id+8 are the two
  // co-halves of one 256-wide m-tile -> B-tile L2 reuse within an XCD.
  const int id = blockIdx.x;
  const int xcd = id & 7;
  const int l = id >> 3;              // 0..97
  const int co0 = (l & 1) * 128;
  const int m0 = ((l >> 1) * 8 + xcd) * 256;

  // ---- staging geometry: thread -> (row = tid>>2, chunk = tid&3) ----
  // LDS chunk c_lds holds global chunk c_lds ^ ((row>>1)&3)  (inverse-swz src)
  const int srow = tid >> 2;                        // 0..63
  const int scol = (tid & 3) ^ ((tid >> 3) & 3);    // pre-swizzled src chunk

  const char* wsrc[2];
#pragma unroll
  for (int i = 0; i < 2; ++i)
    wsrc[i] = wq + (co0 + srow + 64 * i) * 2304 + scol * 16;
  const char* xsrc[4];
#pragma unroll
  for (int i = 0; i < 4; ++i) {
    const int m = m0 + srow + 64 * i;
    const int b = m / HW;
    const int rem = m - b * HW;
    const int y = rem / W_;
    const int x = rem - y * W_;
    xsrc[i] = xp + ((b * HP + y) * WPAD + x) * C_ + scol * 16;
  }

  // stage K-step s (tap = s>>2, ci-quarter q = s&3) into buffer (s&1).
  // 6 x global_load_lds dwordx4 per thread: 2 for A (8KB), 4 for B (16KB).
  auto stage = [&](int s) {
    const int tap = s >> 2;
    const int q = s & 3;
    const int woff = tap * 256 + q * 64;
    const int shoff = ((tap / 3) * WPAD + (tap % 3)) * C_ + q * 64;
    char* dA = sA + (s & 1) * 8192 + tid * 16;
    char* dB = sB + (s & 1) * 16384 + tid * 16;
#pragma unroll
    for (int i = 0; i < 2; ++i)
      GLL16(wsrc[i] + woff, dA + i * 4096);
#pragma unroll
    for (int i = 0; i < 4; ++i)
      GLL16(xsrc[i] + shoff, dB + i * 4096);
  };

  // ---- read-side lane geometry ----
  const int lane = tid & 63;
  const int wn = tid >> 6;        // wave = m 64-quarter; all waves span 128 co
  const int lrow = lane & 15;
  const int kq = lane >> 4;       // k 16B-chunk within K=64
  const int coff = (kq ^ ((lrow >> 1) & 3)) * 16;   // swizzled chunk
  const int abase = lrow * 64 + coff;               // + ii*1024
  const int bbase = (wn * 64 + lrow) * 64 + coff;   // + j*1024

  intx4 acc[8][4] = {};

  stage(0);
#pragma unroll 1
  for (int t = 0; t < 36; ++t) {
    __syncthreads();              // drain: buf[t&1] staged, buf[(t+1)&1] free
    if (t < 35) stage(t + 1);     // in flight during compute(t)
    const char* bA = sA + (t & 1) * 8192;
    const char* bB = sB + (t & 1) * 16384;
    intx4 af[8], bv[4];
#pragma unroll
    for (int ii = 0; ii < 8; ++ii)
      af[ii] = *(const intx4*)(bA + abase + ii * 1024);
#pragma unroll
    for (int j = 0; j < 4; ++j)
      bv[j] = *(const intx4*)(bB + bbase + j * 1024);
    __builtin_amdgcn_s_setprio(1);
#pragma unroll
    for (int ii = 0; ii < 8; ++ii)
#pragma unroll
      for (int j = 0; j < 4; ++j)
        acc[ii][j] = __builtin_amdgcn_mfma_i32_16x16x64_i8(af[ii], bv[j],
                                                           acc[ii][j], 0, 0, 0);
    __builtin_amdgcn_s_setprio(0);
  }

  // ---- epilogue: D row (kq*4+r) = co, D col (lane&15) = m ----
  int ob[4];
#pragma unroll
  for (int j = 0; j < 4; ++j) {
    const int m = m0 + wn * 64 + j * 16 + lrow;
    const int b = m / HW;
    const int rem = m - b * HW;
    const int y = rem / W_;
    const int x = rem - y * W_;
    ob[j] = b * CHW + y * W_ + x;
  }
#pragma unroll
  for (int ii = 0; ii < 8; ++ii) {
#pragma unroll
    for (int r = 0; r < 4; ++r) {
      const int co = co0 + ii * 16 + kq * 4 + r;
      const float sc = alphah[co];
#pragma unroll
      for (int j = 0; j < 4; ++j)
        out[ob[j] + co * HW] = (float)acc[ii][j][r] * sc;
    }
  }
}

// ---------------------------------------------------------------------------
extern "C" void kernel_launch(void* const* d_in, const int* in_sizes, int n_in,
                              void* d_out, int out_size, void* d_ws, size_t ws_size,
                              hipStream_t stream) {
  const float* input = (const float*)d_in[0];
  const float* w1 = (const float*)d_in[1];
  const float* w2 = (const float*)d_in[2];
  float* out = (float*)d_out;

  char* ws = (char*)d_ws;
  char* xp = ws;                                    // 27,557,888 B
  char* wq = ws + XPAD_BYTES;                       // 589,824 B
  float* alphah = (float*)(ws + XPAD_BYTES + WPK_BYTES);  // 1,024 B

  pack_kernel<<<B_ * HP + C_, 256, 0, stream>>>(input, w1, w2, xp, wq, alphah);
  gemm_kernel<<<784, 256, 0, stream>>>(xp, wq, alphah, out);
}

// Round 5
// 325.212 us; speedup vs baseline: 1.3357x; 1.3357x over previous
//
#include <hip/hip_runtime.h>
#include <hip/hip_bf16.h>

// Problem constants
#define B_    32
#define C_    256     // Cin == Cout
#define H_    56
#define W_    56
#define HP    58      // padded H
#define WPAD  58      // padded W
#define HW    3136    // H_*W_
#define CHW   802816  // C_*H_*W_
#define M_TOT 100352  // B_*H_*W_

typedef int intx4 __attribute__((ext_vector_type(4)));

#define XPAD_BYTES (B_ * HP * WPAD * C_)        // 27,557,888 (i8)
#define WPK_BYTES  (C_ * 9 * C_)                // 589,824 (i8)

__device__ __forceinline__ int sgn8(float f) {
  return ((f > 0.f) ? 1 : ((f < 0.f) ? -1 : 0)) & 0xff;
}

// ---------------------------------------------------------------------------
// Merged pack kernel: blocks [0, B_*HP) run the pack_x role (sign(x) NCHW
// fp32 -> padded NHWC i8), blocks [B_*HP, B_*HP+C_) run the pack_w role
// (wq[co][s][ci] i8 = sign(w1)+sign(w2), alphah[co]).
// ---------------------------------------------------------------------------
#define ROWPC 272
__global__ __launch_bounds__(256) void pack_kernel(const float* __restrict__ in,
                                                   const float* __restrict__ w1,
                                                   const float* __restrict__ w2,
                                                   char* __restrict__ xp,
                                                   char* __restrict__ wq,
                                                   float* __restrict__ alphah) {
  __shared__ char smem[18448];
  const int tid = threadIdx.x;

  if (blockIdx.x < B_ * HP) {
    // ---------------- pack_x role ----------------
    char* row = smem;   // 58 * ROWPC = 15776 B
    const int yp = blockIdx.x % HP;
    const int b  = blockIdx.x / HP;

    float4* rz = (float4*)row;
    const float4 z4 = make_float4(0.f, 0.f, 0.f, 0.f);
#pragma unroll
    for (int i = 0; i < 4; ++i) {
      const int idx = i * 256 + tid;
      if (idx < (58 * ROWPC) / 16) rz[idx] = z4;
    }
    __syncthreads();

    const int y = yp - 1;
    const int xq = tid % 14;   // x quad: x = xq*4 .. xq*4+3
    const int cs = tid / 14;   // ci-quad slot 0..18 (252..255 idle)
    if (y >= 0 && y < H_ && cs < 18) {
      const float* base = in + ((size_t)b * C_ * H_ + (size_t)y) * W_ + xq * 4;
#pragma unroll
      for (int k = 0; k < 4; ++k) {
        const int cq = cs + 18 * k;          // ci quad index 0..63
        if (cq < 64) {
          float4 f[4];
#pragma unroll
          for (int j = 0; j < 4; ++j)
            f[j] = *(const float4*)(base + (size_t)(cq * 4 + j) * (H_ * W_));
#pragma unroll
          for (int d = 0; d < 4; ++d) {
            const float v0 = (d == 0) ? f[0].x : (d == 1) ? f[0].y : (d == 2) ? f[0].z : f[0].w;
            const float v1 = (d == 0) ? f[1].x : (d == 1) ? f[1].y : (d == 2) ? f[1].z : f[1].w;
            const float v2 = (d == 0) ? f[2].x : (d == 1) ? f[2].y : (d == 2) ? f[2].z : f[2].w;
            const float v3 = (d == 0) ? f[3].x : (d == 1) ? f[3].y : (d == 2) ? f[3].z : f[3].w;
            const unsigned int pk = (unsigned)sgn8(v0) | ((unsigned)sgn8(v1) << 8) |
                                    ((unsigned)sgn8(v2) << 16) | ((unsigned)sgn8(v3) << 24);
            *(unsigned int*)&row[(xq * 4 + d + 1) * ROWPC + cq * 4] = pk;
          }
        }
      }
    }
    __syncthreads();

    const int cc = tid & 15;   // 16 chunks = full 256 B ci-row
    const int xo = tid >> 4;   // 16 x per iter
    char* dst = xp + (size_t)(b * HP + yp) * WPAD * C_;
#pragma unroll
    for (int it = 0; it < 4; ++it) {
      const int xs = it * 16 + xo;
      if (xs < WPAD)
        *(float4*)(dst + xs * C_ + cc * 16) = *(const float4*)&row[xs * ROWPC + cc * 16];
    }
  } else {
    // ---------------- pack_w role ----------------
    float* l1 = (float*)smem;          // 2304 f
    float* l2 = l1 + 2304;             // 2304 f
    float* red = (float*)(smem + 18432);  // 4 f
    const int co = blockIdx.x - B_ * HP;
    const float* s1 = w1 + co * 2304;
    const float* s2 = w2 + co * 2304;
#pragma unroll
    for (int i = 0; i < 9; ++i) {       // stride-1 across lanes: coalesced
      l1[i * 256 + tid] = s1[i * 256 + tid];
      l2[i * 256 + tid] = s2[i * 256 + tid];
    }
    __syncthreads();
    const int ci = tid;
    float sabs = 0.f;
#pragma unroll
    for (int s = 0; s < 9; ++s) {       // LDS stride 9 (odd) -> bank-spread
      const float a = l1[ci * 9 + s];
      const float b = l2[ci * 9 + s];
      const int sa = (a > 0.f) - (a < 0.f);
      const int sb = (b > 0.f) - (b < 0.f);
      wq[(co * 9 + s) * C_ + ci] = (char)(sa + sb);   // coalesced byte store
      sabs += fabsf(a) + fabsf(b);
    }
#pragma unroll
    for (int off = 32; off > 0; off >>= 1) sabs += __shfl_down(sabs, off, 64);
    if ((tid & 63) == 0) red[tid >> 6] = sabs;
    __syncthreads();
    if (tid == 0)
      alphah[co] = (red[0] + red[1] + red[2] + red[3]) * (0.5f / 2304.0f);
  }
}

// ---------------------------------------------------------------------------
// Implicit-GEMM conv, int8, B-DIRECT: input (B operand) is loaded straight
// global->VGPR (xp is 27.5 MB total = ~3.4 MB per XCD with the paired
// decode -> L2-resident; each load instruction covers 16 rows x 64 B,
// perfectly 64B-line-aligned, no swizzle needed). Only A (weights) goes
// through LDS -> LDS traffic halves vs R0 and A can stage a FULL 256B tap
// per step: 9 barriers instead of 18. Tile 128x128, 4 waves 2x2 of 64x64
// (R0 wave grid + epilogue verbatim). A LDS dbuf 2x32KB = 64 KB ->
// 2 blocks/CU. Registers: acc 64 + bv 64 + af 16 + addr ~ 190 <= 256 at
// (256,2) -- no spill (the R4 lesson). A-swizzle: 16 chunks/row,
// chunk = (q*4+kq) ^ lrow; uniform 8-accesses/bank, rows 256B-aligned --
// same density as R0's measured-0-conflict pattern.
// ---------------------------------------------------------------------------
#define GLL16(src, dst)                                                        \
  __builtin_amdgcn_global_load_lds(                                            \
      (const __attribute__((address_space(1))) void*)(src),                    \
      (__attribute__((address_space(3))) void*)(dst), 16, 0, 0)

__global__ __launch_bounds__(256, 2) void gemm_kernel(const char* __restrict__ xp,
                                                      const char* __restrict__ wq,
                                                      const float* __restrict__ alphah,
                                                      float* __restrict__ out) {
  __shared__ char sA[2 * 128 * 256];   // 64 KB: [buf][co row 128][tap 256B]
  const int tid = threadIdx.x;

  // XCD-paired decode (1568 = 8*196, bijective): blocks id, id+8 are the two
  // co-halves of one m-tile -> shared B rows live in one XCD's L2.
  const int id = blockIdx.x;
  const int xcd = id & 7;
  const int l = id >> 3;              // 0..195
  const int co0 = (l & 1) * 128;
  const int m0 = ((l >> 1) * 8 + xcd) * 128;

  // ---- A staging: thread -> (row16 = tid>>4, chunk = tid&15) ----
  // LDS chunk c of row r holds global chunk c ^ (r & 15)  (inverse-swz src).
  const int srow16 = tid >> 4;                       // row within 16-group
  const int schunk = (tid & 15) ^ srow16;            // pre-swizzled src chunk
  const char* awsrc = wq + (co0 + srow16) * 2304 + schunk * 16;

  // stage tap t (full 256 B of all 128 co rows) into buffer buf.
  // 8 x global_load_lds dwordx4 per thread (32 KB block total).
  auto stageA = [&](int t, int buf) {
    const int off = t * 256;
    char* d = sA + buf * 32768 + tid * 16;
#pragma unroll
    for (int i = 0; i < 8; ++i)                      // rows i*16 + srow16
      GLL16(awsrc + off + i * 36864, d + i * 4096);  // 36864 = 16*2304
  };

  // ---- lane geometry (R0 wave grid) ----
  const int lane = tid & 63;
  const int wave = tid >> 6;
  const int wm = wave >> 1;       // co 64-half
  const int wn = wave & 1;        // m 64-half
  const int lrow = lane & 15;
  const int kq = lane >> 4;       // 16B k-chunk within K=64

  // B row bases: lane (lrow,kq) reads xp[m-row][tap + q*64 + kq*16] directly.
  const char* xrow[4];
#pragma unroll
  for (int j = 0; j < 4; ++j) {
    const int m = m0 + wn * 64 + j * 16 + lrow;
    const int b = m / HW;
    const int rem = m - b * HW;
    const int y = rem / W_;
    const int x = rem - y * W_;
    xrow[j] = xp + ((b * HP + y) * WPAD + x) * C_ + kq * 16;
  }

  const int abase = (wm * 64 + lrow) * 256;   // + ii*4096 + swz-chunk*16

  intx4 acc[4][4] = {};

  stageA(0, 0);
#pragma unroll 1
  for (int t = 0; t < 9; ++t) {
    __syncthreads();             // A buf[t&1] staged; buf[(t+1)&1] reads done
    const int shoff = ((t / 3) * WPAD + (t % 3)) * C_;   // scalar tap shift

    // B for the whole tap: 16 x global_load_dwordx4 (L2-resident), issued
    // first (latency-critical, consumed this tap).
    intx4 bv[4][4];
#pragma unroll
    for (int q = 0; q < 4; ++q)
#pragma unroll
      for (int j = 0; j < 4; ++j)
        bv[q][j] = *(const intx4*)(xrow[j] + shoff + q * 64);

    if (t < 8) stageA(t + 1, (t + 1) & 1);   // in flight during compute(t)

    const char* bA = sA + (t & 1) * 32768 + abase;
#pragma unroll
    for (int q = 0; q < 4; ++q) {
      intx4 af[4];
#pragma unroll
      for (int ii = 0; ii < 4; ++ii)
        af[ii] = *(const intx4*)(bA + ii * 4096 + (((q * 4 + kq) ^ lrow) * 16));
      __builtin_amdgcn_s_setprio(1);
#pragma unroll
      for (int ii = 0; ii < 4; ++ii)
#pragma unroll
        for (int j = 0; j < 4; ++j)
          acc[ii][j] = __builtin_amdgcn_mfma_i32_16x16x64_i8(af[ii], bv[q][j],
                                                             acc[ii][j], 0, 0, 0);
      __builtin_amdgcn_s_setprio(0);
    }
  }

  // ---- epilogue (R0 verbatim): D row (kq*4+r) = co, D col (lane&15) = m ----
  int ob[4];
#pragma unroll
  for (int j = 0; j < 4; ++j) {
    const int m = m0 + wn * 64 + j * 16 + lrow;
    const int b = m / HW;
    const int rem = m - b * HW;
    const int y = rem / W_;
    const int x = rem - y * W_;
    ob[j] = b * CHW + y * W_ + x;
  }
#pragma unroll
  for (int ii = 0; ii < 4; ++ii) {
#pragma unroll
    for (int r = 0; r < 4; ++r) {
      const int co = co0 + wm * 64 + ii * 16 + kq * 4 + r;
      const float sc = alphah[co];
#pragma unroll
      for (int j = 0; j < 4; ++j)
        out[ob[j] + co * HW] = (float)acc[ii][j][r] * sc;
    }
  }
}

// ---------------------------------------------------------------------------
extern "C" void kernel_launch(void* const* d_in, const int* in_sizes, int n_in,
                              void* d_out, int out_size, void* d_ws, size_t ws_size,
                              hipStream_t stream) {
  const float* input = (const float*)d_in[0];
  const float* w1 = (const float*)d_in[1];
  const float* w2 = (const float*)d_in[2];
  float* out = (float*)d_out;

  char* ws = (char*)d_ws;
  char* xp = ws;                                    // 27,557,888 B
  char* wq = ws + XPAD_BYTES;                       // 589,824 B
  float* alphah = (float*)(ws + XPAD_BYTES + WPK_BYTES);  // 1,024 B

  pack_kernel<<<B_ * HP + C_, 256, 0, stream>>>(input, w1, w2, xp, wq, alphah);
  gemm_kernel<<<1568, 256, 0, stream>>>(xp, wq, alphah, out);
}

// Round 6
// 261.268 us; speedup vs baseline: 1.6627x; 1.2447x over previous
//
#include <hip/hip_runtime.h>
#include <hip/hip_bf16.h>

// Problem constants
#define B_    32
#define C_    256     // Cin == Cout
#define H_    56
#define W_    56
#define HP    58      // padded H
#define WPAD  58      // padded W
#define HW    3136    // H_*W_
#define CHW   802816  // C_*H_*W_
#define M_TOT 100352  // B_*H_*W_

typedef int intx4 __attribute__((ext_vector_type(4)));

#define XPAD_BYTES (B_ * HP * WPAD * C_)        // 27,557,888 (i8)
#define WPK_BYTES  (C_ * 9 * C_)                // 589,824 (i8)

__device__ __forceinline__ int sgn8(float f) {
  return ((f > 0.f) ? 1 : ((f < 0.f) ? -1 : 0)) & 0xff;
}

// ---------------------------------------------------------------------------
// Merged pack kernel: blocks [0, B_*HP) run the pack_x role (sign(x) NCHW
// fp32 -> padded NHWC i8), blocks [B_*HP, B_*HP+C_) run the pack_w role
// (wq[co][s][ci] i8 = sign(w1)+sign(w2), alphah[co]).
// ---------------------------------------------------------------------------
#define ROWPC 272
__global__ __launch_bounds__(256) void pack_kernel(const float* __restrict__ in,
                                                   const float* __restrict__ w1,
                                                   const float* __restrict__ w2,
                                                   char* __restrict__ xp,
                                                   char* __restrict__ wq,
                                                   float* __restrict__ alphah) {
  __shared__ char smem[18448];
  const int tid = threadIdx.x;

  if (blockIdx.x < B_ * HP) {
    // ---------------- pack_x role ----------------
    char* row = smem;   // 58 * ROWPC = 15776 B
    const int yp = blockIdx.x % HP;
    const int b  = blockIdx.x / HP;

    float4* rz = (float4*)row;
    const float4 z4 = make_float4(0.f, 0.f, 0.f, 0.f);
#pragma unroll
    for (int i = 0; i < 4; ++i) {
      const int idx = i * 256 + tid;
      if (idx < (58 * ROWPC) / 16) rz[idx] = z4;
    }
    __syncthreads();

    const int y = yp - 1;
    const int xq = tid % 14;   // x quad: x = xq*4 .. xq*4+3
    const int cs = tid / 14;   // ci-quad slot 0..18 (252..255 idle)
    if (y >= 0 && y < H_ && cs < 18) {
      const float* base = in + ((size_t)b * C_ * H_ + (size_t)y) * W_ + xq * 4;
#pragma unroll
      for (int k = 0; k < 4; ++k) {
        const int cq = cs + 18 * k;          // ci quad index 0..63
        if (cq < 64) {
          float4 f[4];
#pragma unroll
          for (int j = 0; j < 4; ++j)
            f[j] = *(const float4*)(base + (size_t)(cq * 4 + j) * (H_ * W_));
#pragma unroll
          for (int d = 0; d < 4; ++d) {
            const float v0 = (d == 0) ? f[0].x : (d == 1) ? f[0].y : (d == 2) ? f[0].z : f[0].w;
            const float v1 = (d == 0) ? f[1].x : (d == 1) ? f[1].y : (d == 2) ? f[1].z : f[1].w;
            const float v2 = (d == 0) ? f[2].x : (d == 1) ? f[2].y : (d == 2) ? f[2].z : f[2].w;
            const float v3 = (d == 0) ? f[3].x : (d == 1) ? f[3].y : (d == 2) ? f[3].z : f[3].w;
            const unsigned int pk = (unsigned)sgn8(v0) | ((unsigned)sgn8(v1) << 8) |
                                    ((unsigned)sgn8(v2) << 16) | ((unsigned)sgn8(v3) << 24);
            *(unsigned int*)&row[(xq * 4 + d + 1) * ROWPC + cq * 4] = pk;
          }
        }
      }
    }
    __syncthreads();

    const int cc = tid & 15;   // 16 chunks = full 256 B ci-row
    const int xo = tid >> 4;   // 16 x per iter
    char* dst = xp + (size_t)(b * HP + yp) * WPAD * C_;
#pragma unroll
    for (int it = 0; it < 4; ++it) {
      const int xs = it * 16 + xo;
      if (xs < WPAD)
        *(float4*)(dst + xs * C_ + cc * 16) = *(const float4*)&row[xs * ROWPC + cc * 16];
    }
  } else {
    // ---------------- pack_w role ----------------
    float* l1 = (float*)smem;          // 2304 f
    float* l2 = l1 + 2304;             // 2304 f
    float* red = (float*)(smem + 18432);  // 4 f
    const int co = blockIdx.x - B_ * HP;
    const float* s1 = w1 + co * 2304;
    const float* s2 = w2 + co * 2304;
#pragma unroll
    for (int i = 0; i < 9; ++i) {       // stride-1 across lanes: coalesced
      l1[i * 256 + tid] = s1[i * 256 + tid];
      l2[i * 256 + tid] = s2[i * 256 + tid];
    }
    __syncthreads();
    const int ci = tid;
    float sabs = 0.f;
#pragma unroll
    for (int s = 0; s < 9; ++s) {       // LDS stride 9 (odd) -> bank-spread
      const float a = l1[ci * 9 + s];
      const float b = l2[ci * 9 + s];
      const int sa = (a > 0.f) - (a < 0.f);
      const int sb = (b > 0.f) - (b < 0.f);
      wq[(co * 9 + s) * C_ + ci] = (char)(sa + sb);   // coalesced byte store
      sabs += fabsf(a) + fabsf(b);
    }
#pragma unroll
    for (int off = 32; off > 0; off >>= 1) sabs += __shfl_down(sabs, off, 64);
    if ((tid & 63) == 0) red[tid >> 6] = sabs;
    __syncthreads();
    if (tid == 0)
      alphah[co] = (red[0] + red[1] + red[2] + red[3]) * (0.5f / 2304.0f);
  }
}

// ---------------------------------------------------------------------------
// Implicit-GEMM conv, int8 -- EXACT round-0 structure (75 us verified):
// double-buffered, one barrier per K-step, tile 128(co) x 128(m), 4 waves
// of 64x64, mfma_i32_16x16x64_i8, 18 steps (9 taps x 2 ci-halves), LDS
// 64 KB -> 2 blocks/CU, XOR-chunk swizzle (0 conflicts), XCD-paired decode.
// ONE new variable: entry-time jitter (hash(blockIdx) x ~512 cyc s_sleep)
// to ANTI-PHASE the two co-resident blocks. Theory: R0's measured 3270
// cyc/step == LDS(1900) + MFMA(1300) run SERIALLY because both blocks hit
// their ds_read burst and MFMA burst in lockstep (dispatch starts them
// simultaneously; contention provides no restoring force). Anti-phased,
// the CU window would be ~max(LDS, MFMA) ~ 2000 cyc/step. Jitter is pure
// timing -- zero correctness risk, ~+1 us worst case.
// ---------------------------------------------------------------------------
#define GLL16(src, dst)                                                        \
  __builtin_amdgcn_global_load_lds(                                            \
      (const __attribute__((address_space(1))) void*)(src),                    \
      (__attribute__((address_space(3))) void*)(dst), 16, 0, 0)

__global__ __launch_bounds__(256, 2) void gemm_kernel(const char* __restrict__ xp,
                                                      const char* __restrict__ wq,
                                                      const float* __restrict__ alphah,
                                                      float* __restrict__ out) {
  __shared__ char sA[2 * 128 * 128];  // weight tiles [buf][co 128][k 128B]
  __shared__ char sB[2 * 128 * 128];  // input tiles  [buf][m 128][k 128B]
  const int tid = threadIdx.x;

  // XCD-paired decode: blocks id, id+8 are the two co-halves of one m-tile.
  const int id = blockIdx.x;

  // ---- entry jitter: desynchronize co-resident blocks (see header) ----
  {
    const int ph = (id ^ (id >> 3) ^ (id >> 6) ^ (id >> 9)) & 3;
    for (int i = 0; i < ph; ++i) __builtin_amdgcn_s_sleep(8);  // ~512 cyc each
  }

  const int xcd = id & 7;
  const int l = id >> 3;
  const int co0 = (l & 1) * 128;
  const int m0 = ((l >> 1) * 8 + xcd) * 128;

  const int srow = tid >> 3;                 // staging row 0..31 (+32*i)
  const int scol = (tid & 7) ^ (srow & 7);   // XOR-swizzled source chunk

  const char* wsrc[4];
  const char* xsrc[4];
#pragma unroll
  for (int i = 0; i < 4; ++i) {
    const int m = m0 + srow + 32 * i;
    const int b = m / HW;
    const int rem = m - b * HW;
    const int y = rem / W_;
    const int x = rem - y * W_;
    xsrc[i] = xp + ((b * HP + y) * WPAD + x) * C_ + scol * 16;
    wsrc[i] = wq + (co0 + srow + 32 * i) * 9 * C_ + scol * 16;
  }

  intx4 acc[4][4] = {};

  const int lane = tid & 63;
  const int wave = tid >> 6;
  const int wm = wave >> 1;   // co 64-half
  const int wn = wave & 1;    // m 64-half
  const int lrow = lane & 15;
  const int quad = lane >> 4;
  const int swk = lrow & 7;
  const int abase = (wm * 64 + lrow) * 128;
  const int bbase = (wn * 64 + lrow) * 128;

  // stage tile t (s = t>>1, h = t&1) into buffer (t&1)
  auto stage = [&](int t) {
    const int s = t >> 1;
    const int hh = (t & 1) * 128;
    const int woff = s * C_ + hh;
    const int shoff = ((s / 3) * WPAD + (s % 3)) * C_ + hh;
    char* dA = sA + (t & 1) * 16384 + tid * 16;
    char* dB = sB + (t & 1) * 16384 + tid * 16;
#pragma unroll
    for (int i = 0; i < 4; ++i)
      GLL16(wsrc[i] + woff, dA + i * 4096);
#pragma unroll
    for (int i = 0; i < 4; ++i)
      GLL16(xsrc[i] + shoff, dB + i * 4096);
  };

  stage(0);
#pragma unroll 1
  for (int t = 0; t < 18; ++t) {
    __syncthreads();            // vmcnt(0)+lgkmcnt drain: buf[t&1] ready,
                                // buf[(t+1)&1] reads (step t-1) complete
    if (t < 17) stage(t + 1);   // in flight during compute(t)
    const char* bA = sA + (t & 1) * 16384;
    const char* bB = sB + (t & 1) * 16384;
#pragma unroll
    for (int kf = 0; kf < 2; ++kf) {
      const int coff = (((kf << 2) + quad) ^ swk) << 4;  // swizzled chunk
      intx4 af[4], bfv[4];
#pragma unroll
      for (int i = 0; i < 4; ++i)
        af[i] = *(const intx4*)(bA + abase + i * 2048 + coff);
#pragma unroll
      for (int j = 0; j < 4; ++j)
        bfv[j] = *(const intx4*)(bB + bbase + j * 2048 + coff);
#pragma unroll
      for (int i = 0; i < 4; ++i)
#pragma unroll
        for (int j = 0; j < 4; ++j)
          acc[i][j] = __builtin_amdgcn_mfma_i32_16x16x64_i8(af[i], bfv[j],
                                                            acc[i][j], 0, 0, 0);
    }
  }

  // Epilogue: D row (quad*4+r) = co dim, D col (lane&15) = spatial m dim.
  int ob[4];
#pragma unroll
  for (int j = 0; j < 4; ++j) {
    const int m = m0 + wn * 64 + j * 16 + lrow;
    const int b = m / HW;
    const int rem = m - b * HW;
    const int y = rem / W_;
    const int x = rem - y * W_;
    ob[j] = b * CHW + y * W_ + x;
  }
#pragma unroll
  for (int i = 0; i < 4; ++i) {
#pragma unroll
    for (int r = 0; r < 4; ++r) {
      const int co = co0 + wm * 64 + i * 16 + quad * 4 + r;
      const float sc = alphah[co];
#pragma unroll
      for (int j = 0; j < 4; ++j)
        out[ob[j] + co * HW] = (float)acc[i][j][r] * sc;
    }
  }
}

// ---------------------------------------------------------------------------
extern "C" void kernel_launch(void* const* d_in, const int* in_sizes, int n_in,
                              void* d_out, int out_size, void* d_ws, size_t ws_size,
                              hipStream_t stream) {
  const float* input = (const float*)d_in[0];
  const float* w1 = (const float*)d_in[1];
  const float* w2 = (const float*)d_in[2];
  float* out = (float*)d_out;

  char* ws = (char*)d_ws;
  char* xp = ws;                                    // 27,557,888 B
  char* wq = ws + XPAD_BYTES;                       // 589,824 B
  float* alphah = (float*)(ws + XPAD_BYTES + WPK_BYTES);  // 1,024 B

  pack_kernel<<<B_ * HP + C_, 256, 0, stream>>>(input, w1, w2, xp, wq, alphah);
  gemm_kernel<<<M_TOT / 128 * (C_ / 128), 256, 0, stream>>>(xp, wq, alphah, out);
}

// Round 7
// 244.736 us; speedup vs baseline: 1.7750x; 1.0676x over previous
//
#include <hip/hip_runtime.h>
#include <hip/hip_bf16.h>

// Problem constants
#define B_    32
#define C_    256     // Cin == Cout
#define H_    56
#define W_    56
#define HP    58      // padded H
#define WPAD  58      // padded W
#define HW    3136    // H_*W_
#define CHW   802816  // C_*H_*W_
#define M_TOT 100352  // B_*H_*W_

typedef int intx4 __attribute__((ext_vector_type(4)));

#define XPAD_BYTES (B_ * HP * WPAD * C_)        // 27,557,888 (i8)
#define WPK_BYTES  (C_ * 9 * C_)                // 589,824 (i8)

__device__ __forceinline__ int sgn8(float f) {
  return ((f > 0.f) ? 1 : ((f < 0.f) ? -1 : 0)) & 0xff;
}

// ---------------------------------------------------------------------------
// Merged pack kernel: blocks [0, B_*HP) run the pack_x role (sign(x) NCHW
// fp32 -> padded NHWC i8), blocks [B_*HP, B_*HP+C_) run the pack_w role
// (wq[co][s][ci] i8 = sign(w1)+sign(w2), alphah[co]). Validated R3-R6:
// saves ~3.5 us vs separate launches, results identical.
// ---------------------------------------------------------------------------
#define ROWPC 272
__global__ __launch_bounds__(256) void pack_kernel(const float* __restrict__ in,
                                                   const float* __restrict__ w1,
                                                   const float* __restrict__ w2,
                                                   char* __restrict__ xp,
                                                   char* __restrict__ wq,
                                                   float* __restrict__ alphah) {
  __shared__ char smem[18448];
  const int tid = threadIdx.x;

  if (blockIdx.x < B_ * HP) {
    // ---------------- pack_x role ----------------
    char* row = smem;   // 58 * ROWPC = 15776 B
    const int yp = blockIdx.x % HP;
    const int b  = blockIdx.x / HP;

    float4* rz = (float4*)row;
    const float4 z4 = make_float4(0.f, 0.f, 0.f, 0.f);
#pragma unroll
    for (int i = 0; i < 4; ++i) {
      const int idx = i * 256 + tid;
      if (idx < (58 * ROWPC) / 16) rz[idx] = z4;
    }
    __syncthreads();

    const int y = yp - 1;
    const int xq = tid % 14;   // x quad: x = xq*4 .. xq*4+3
    const int cs = tid / 14;   // ci-quad slot 0..18 (252..255 idle)
    if (y >= 0 && y < H_ && cs < 18) {
      const float* base = in + ((size_t)b * C_ * H_ + (size_t)y) * W_ + xq * 4;
#pragma unroll
      for (int k = 0; k < 4; ++k) {
        const int cq = cs + 18 * k;          // ci quad index 0..63
        if (cq < 64) {
          float4 f[4];
#pragma unroll
          for (int j = 0; j < 4; ++j)
            f[j] = *(const float4*)(base + (size_t)(cq * 4 + j) * (H_ * W_));
#pragma unroll
          for (int d = 0; d < 4; ++d) {
            const float v0 = (d == 0) ? f[0].x : (d == 1) ? f[0].y : (d == 2) ? f[0].z : f[0].w;
            const float v1 = (d == 0) ? f[1].x : (d == 1) ? f[1].y : (d == 2) ? f[1].z : f[1].w;
            const float v2 = (d == 0) ? f[2].x : (d == 1) ? f[2].y : (d == 2) ? f[2].z : f[2].w;
            const float v3 = (d == 0) ? f[3].x : (d == 1) ? f[3].y : (d == 2) ? f[3].z : f[3].w;
            const unsigned int pk = (unsigned)sgn8(v0) | ((unsigned)sgn8(v1) << 8) |
                                    ((unsigned)sgn8(v2) << 16) | ((unsigned)sgn8(v3) << 24);
            *(unsigned int*)&row[(xq * 4 + d + 1) * ROWPC + cq * 4] = pk;
          }
        }
      }
    }
    __syncthreads();

    const int cc = tid & 15;   // 16 chunks = full 256 B ci-row
    const int xo = tid >> 4;   // 16 x per iter
    char* dst = xp + (size_t)(b * HP + yp) * WPAD * C_;
#pragma unroll
    for (int it = 0; it < 4; ++it) {
      const int xs = it * 16 + xo;
      if (xs < WPAD)
        *(float4*)(dst + xs * C_ + cc * 16) = *(const float4*)&row[xs * ROWPC + cc * 16];
    }
  } else {
    // ---------------- pack_w role ----------------
    float* l1 = (float*)smem;          // 2304 f
    float* l2 = l1 + 2304;             // 2304 f
    float* red = (float*)(smem + 18432);  // 4 f
    const int co = blockIdx.x - B_ * HP;
    const float* s1 = w1 + co * 2304;
    const float* s2 = w2 + co * 2304;
#pragma unroll
    for (int i = 0; i < 9; ++i) {       // stride-1 across lanes: coalesced
      l1[i * 256 + tid] = s1[i * 256 + tid];
      l2[i * 256 + tid] = s2[i * 256 + tid];
    }
    __syncthreads();
    const int ci = tid;
    float sabs = 0.f;
#pragma unroll
    for (int s = 0; s < 9; ++s) {       // LDS stride 9 (odd) -> bank-spread
      const float a = l1[ci * 9 + s];
      const float b = l2[ci * 9 + s];
      const int sa = (a > 0.f) - (a < 0.f);
      const int sb = (b > 0.f) - (b < 0.f);
      wq[(co * 9 + s) * C_ + ci] = (char)(sa + sb);   // coalesced byte store
      sabs += fabsf(a) + fabsf(b);
    }
#pragma unroll
    for (int off = 32; off > 0; off >>= 1) sabs += __shfl_down(sabs, off, 64);
    if ((tid & 63) == 0) red[tid >> 6] = sabs;
    __syncthreads();
    if (tid == 0)
      alphah[co] = (red[0] + red[1] + red[2] + red[3]) * (0.5f / 2304.0f);
  }
}

// ---------------------------------------------------------------------------
// Implicit-GEMM conv, int8 -- BYTE-EXACT round-0 gemm (75 us verified):
// double-buffered, one barrier per K-step, tile 128(co) x 128(m), 4 waves
// of 64x64, mfma_i32_16x16x64_i8, 18 steps, LDS 64 KB -> 2 blocks/CU,
// XOR-chunk swizzle (0 conflicts), XCD-paired decode. NO unroll pragma on
// the main loop: the compiler's 2x unroll statically resolves (t&1) buffer
// parity (R6 lesson: forcing unroll-1 cost +35% VALU cycles, +16 us).
// No entry jitter (R6: phase-lock theory unsupported).
// ---------------------------------------------------------------------------
#define GLL16(src, dst)                                                        \
  __builtin_amdgcn_global_load_lds(                                            \
      (const __attribute__((address_space(1))) void*)(src),                    \
      (__attribute__((address_space(3))) void*)(dst), 16, 0, 0)

__global__ __launch_bounds__(256, 2) void gemm_kernel(const char* __restrict__ xp,
                                                      const char* __restrict__ wq,
                                                      const float* __restrict__ alphah,
                                                      float* __restrict__ out) {
  __shared__ char sA[2 * 128 * 128];  // weight tiles [buf][co 128][k 128B]
  __shared__ char sB[2 * 128 * 128];  // input tiles  [buf][m 128][k 128B]
  const int tid = threadIdx.x;

  // XCD-paired decode: blocks id, id+8 are the two co-halves of one m-tile.
  const int id = blockIdx.x;
  const int xcd = id & 7;
  const int l = id >> 3;
  const int co0 = (l & 1) * 128;
  const int m0 = ((l >> 1) * 8 + xcd) * 128;

  const int srow = tid >> 3;                 // staging row 0..31 (+32*i)
  const int scol = (tid & 7) ^ (srow & 7);   // XOR-swizzled source chunk

  const char* wsrc[4];
  const char* xsrc[4];
#pragma unroll
  for (int i = 0; i < 4; ++i) {
    const int m = m0 + srow + 32 * i;
    const int b = m / HW;
    const int rem = m - b * HW;
    const int y = rem / W_;
    const int x = rem - y * W_;
    xsrc[i] = xp + ((b * HP + y) * WPAD + x) * C_ + scol * 16;
    wsrc[i] = wq + (co0 + srow + 32 * i) * 9 * C_ + scol * 16;
  }

  intx4 acc[4][4] = {};

  const int lane = tid & 63;
  const int wave = tid >> 6;
  const int wm = wave >> 1;   // co 64-half
  const int wn = wave & 1;    // m 64-half
  const int lrow = lane & 15;
  const int quad = lane >> 4;
  const int swk = lrow & 7;
  const int abase = (wm * 64 + lrow) * 128;
  const int bbase = (wn * 64 + lrow) * 128;

  // stage tile t (s = t>>1, h = t&1) into buffer (t&1)
  auto stage = [&](int t) {
    const int s = t >> 1;
    const int hh = (t & 1) * 128;
    const int woff = s * C_ + hh;
    const int shoff = ((s / 3) * WPAD + (s % 3)) * C_ + hh;
    char* dA = sA + (t & 1) * 16384 + tid * 16;
    char* dB = sB + (t & 1) * 16384 + tid * 16;
#pragma unroll
    for (int i = 0; i < 4; ++i)
      GLL16(wsrc[i] + woff, dA + i * 4096);
#pragma unroll
    for (int i = 0; i < 4; ++i)
      GLL16(xsrc[i] + shoff, dB + i * 4096);
  };

  stage(0);
  for (int t = 0; t < 18; ++t) {
    __syncthreads();            // vmcnt(0)+lgkmcnt drain: buf[t&1] ready,
                                // buf[(t+1)&1] reads (step t-1) complete
    if (t < 17) stage(t + 1);   // in flight during compute(t)
    const char* bA = sA + (t & 1) * 16384;
    const char* bB = sB + (t & 1) * 16384;
#pragma unroll
    for (int kf = 0; kf < 2; ++kf) {
      const int coff = (((kf << 2) + quad) ^ swk) << 4;  // swizzled chunk
      intx4 af[4], bfv[4];
#pragma unroll
      for (int i = 0; i < 4; ++i)
        af[i] = *(const intx4*)(bA + abase + i * 2048 + coff);
#pragma unroll
      for (int j = 0; j < 4; ++j)
        bfv[j] = *(const intx4*)(bB + bbase + j * 2048 + coff);
#pragma unroll
      for (int i = 0; i < 4; ++i)
#pragma unroll
        for (int j = 0; j < 4; ++j)
          acc[i][j] = __builtin_amdgcn_mfma_i32_16x16x64_i8(af[i], bfv[j],
                                                            acc[i][j], 0, 0, 0);
    }
  }

  // Epilogue: D row (quad*4+r) = co dim, D col (lane&15) = spatial m dim.
  int ob[4];
#pragma unroll
  for (int j = 0; j < 4; ++j) {
    const int m = m0 + wn * 64 + j * 16 + lrow;
    const int b = m / HW;
    const int rem = m - b * HW;
    const int y = rem / W_;
    const int x = rem - y * W_;
    ob[j] = b * CHW + y * W_ + x;
  }
#pragma unroll
  for (int i = 0; i < 4; ++i) {
#pragma unroll
    for (int r = 0; r < 4; ++r) {
      const int co = co0 + wm * 64 + i * 16 + quad * 4 + r;
      const float sc = alphah[co];
#pragma unroll
      for (int j = 0; j < 4; ++j)
        out[ob[j] + co * HW] = (float)acc[i][j][r] * sc;
    }
  }
}

// ---------------------------------------------------------------------------
extern "C" void kernel_launch(void* const* d_in, const int* in_sizes, int n_in,
                              void* d_out, int out_size, void* d_ws, size_t ws_size,
                              hipStream_t stream) {
  const float* input = (const float*)d_in[0];
  const float* w1 = (const float*)d_in[1];
  const float* w2 = (const float*)d_in[2];
  float* out = (float*)d_out;

  char* ws = (char*)d_ws;
  char* xp = ws;                                    // 27,557,888 B
  char* wq = ws + XPAD_BYTES;                       // 589,824 B
  float* alphah = (float*)(ws + XPAD_BYTES + WPK_BYTES);  // 1,024 B

  pack_kernel<<<B_ * HP + C_, 256, 0, stream>>>(input, w1, w2, xp, wq, alphah);
  gemm_kernel<<<M_TOT / 128 * (C_ / 128), 256, 0, stream>>>(xp, wq, alphah, out);
}